// Round 3
// baseline (127.128 us; speedup 1.0000x reference)
//
#include <hip/hip_runtime.h>
#include <hip/hip_bf16.h>

typedef unsigned long long u64;
typedef unsigned short u16;
typedef __attribute__((ext_vector_type(8))) short short8;
typedef __attribute__((ext_vector_type(4))) float float4_t;

#define BB 8
#define SS 512
#define DD 256
#define HH 4
#define TT 20
#define BS (BB*SS)   /* 4096 tokens */

// d_out layout (floats): out[BS*DD], reg[1], Ti[BS], W[BB*HH*SS*SS]
#define REG_OFF (BS*DD)
#define TI_OFF  (REG_OFF+1)
#define W_OFF   (TI_OFF+BS)

static __device__ __forceinline__ u16 f2bf(float f) {
    __hip_bfloat16 h = __float2bfloat16(f);
    return *reinterpret_cast<u16*>(&h);
}

// ===================== Kernel G: gate MLP -> Ti (computed ONCE) =====================
// 512 blocks x 256 thr; 8 tokens/block (tok = tid>>5, c = tid&31)
__global__ __launch_bounds__(256) void k_gate(
    const float* __restrict__ x,
    const float* __restrict__ Wg1, const float* __restrict__ bg1,
    const float* __restrict__ Wg2, const float* __restrict__ bg2,
    float* __restrict__ ti_out)
{
    __shared__ float xl[8][DD];   // 8 KB
    const int tid  = threadIdx.x;
    const int tok0 = blockIdx.x * 8;
    #pragma unroll
    for (int m = 0; m < 8; ++m) xl[m][tid] = x[(size_t)(tok0+m)*DD + tid];
    __syncthreads();

    const int tok = tid >> 5, c = tid & 31;
    float acc = bg1[c];
    #pragma unroll 4
    for (int r = 0; r < DD; ++r) acc += xl[tok][r] * Wg1[r*32 + c];
    float hrelu = acc > 0.f ? acc : 0.f;
    float term  = hrelu * Wg2[c];
    #pragma unroll
    for (int msk = 16; msk >= 1; msk >>= 1) term += __shfl_xor(term, msk, 64);
    if (c == 0) {
        float g  = term + bg2[0];
        float sg = 1.f / (1.f + expf(-g));
        int ti = (int)ceilf(sg * (float)TT);
        ti = ti < 1 ? 1 : (ti > TT ? TT : ti);
        ti_out[tok0 + tok] = (float)ti;
    }
}

// ===================== Kernel A: one projection + LIF =====================
// grid (512, 3): blockIdx.x = token tile (8 tokens), blockIdx.y = projection (0=q,1=k,2=v)
__global__ __launch_bounds__(256) void k_proj_lif(
    const float* __restrict__ x, const float* __restrict__ Wq,
    const float* __restrict__ Wk, const float* __restrict__ Wv,
    const float* __restrict__ aq, const float* __restrict__ bq_,
    const float* __restrict__ ak, const float* __restrict__ bk_,
    const float* __restrict__ av, const float* __restrict__ bv_,
    const float* __restrict__ ti_in,
    u64* __restrict__ qpack, u64* __restrict__ kpack,
    u16* __restrict__ vmb)
{
    __shared__ float xl[DD][8];   // 8 KB, transposed: row r, token m
    __shared__ int til[8];
    const int tid  = threadIdx.x;
    const int proj = blockIdx.y;
    const int tok0 = blockIdx.x * 8;

    #pragma unroll
    for (int m = 0; m < 8; ++m) xl[tid][m] = x[(size_t)(tok0+m)*DD + tid];
    if (tid < 8) til[tid] = (int)ti_in[tok0 + tid];
    __syncthreads();

    const float* W    = proj == 0 ? Wq  : (proj == 1 ? Wk  : Wv);
    const float alpha = proj == 0 ? *aq : (proj == 1 ? *ak : *av);
    const float beta  = proj == 0 ? *bq_: (proj == 1 ? *bk_: *bv_);

    float acc[8] = {0,0,0,0,0,0,0,0};
    #pragma unroll 4
    for (int r = 0; r < DD; ++r) {
        float w = W[r*DD + tid];
        float4_t x0 = *reinterpret_cast<const float4_t*>(&xl[r][0]);
        float4_t x1 = *reinterpret_cast<const float4_t*>(&xl[r][4]);
        acc[0] += x0.x*w; acc[1] += x0.y*w; acc[2] += x0.z*w; acc[3] += x0.w*w;
        acc[4] += x1.x*w; acc[5] += x1.y*w; acc[6] += x1.z*w; acc[7] += x1.w*w;
    }

    const int lane = tid & 63;
    const int h    = tid >> 6;      // wave = head
    u64* pack = (proj == 0) ? qpack : kpack;

    if (proj < 2) {
        for (int i = 0; i < 8; ++i) {
            int ti = til[i];
            float vv = 0.f, cur = 0.f;
            u64 myw = 0ull;
            #pragma unroll
            for (int t = 0; t < TT; ++t) {
                cur = alpha*cur + acc[i];
                vv  = beta*vv + cur;
                bool s = (vv >= 1.f);
                u64 bal = __ballot(s);
                if (s) vv = 0.f;
                if (lane == t && t < ti) myw = bal;
            }
            if (lane < TT) pack[((size_t)(tok0+i)*HH + h)*TT + lane] = myw;
        }
    } else {
        for (int i = 0; i < 8; ++i) {
            int ti = til[i];
            float vv = 0.f, cur = 0.f;
            float cnt = 0.f;
            #pragma unroll
            for (int t = 0; t < TT; ++t) {
                cur = alpha*cur + acc[i];
                vv  = beta*vv + cur;
                bool s = (vv >= 1.f);
                if (s) { vv = 0.f; if (t < ti) cnt += 1.f; }
            }
            vmb[(size_t)(tok0+i)*DD + tid] = f2bf(cnt * 0.05f);
        }
    }
}

// ===================== Kernel B: reg = 1e-3 * mean(Ti) =====================
__global__ __launch_bounds__(256) void k_reg(const float* __restrict__ ti, float* __restrict__ reg)
{
    __shared__ float ps[4];
    int tid = threadIdx.x;
    float s = 0.f;
    for (int m = 0; m < 16; ++m) s += ti[m*256 + tid];
    for (int msk = 32; msk >= 1; msk >>= 1) s += __shfl_xor(s, msk, 64);
    if ((tid & 63) == 0) ps[tid >> 6] = s;
    __syncthreads();
    if (tid == 0) reg[0] = 1e-3f * (ps[0]+ps[1]+ps[2]+ps[3]) / 4096.f;
}

// ===================== Kernel C: popcount scores + softmax + W + PV (MFMA) ===========
__global__ __launch_bounds__(256) void k_attn(
    const u64* __restrict__ qpack, const u64* __restrict__ kpack,
    const u16* __restrict__ vmb,
    float* __restrict__ Wout, float* __restrict__ attn)
{
    __shared__ u64 ql[16][TT];                 // 2.5 KB
    __shared__ __align__(16) u16 CP[16*SS];    // 16 KB: counts, then P (bf16, swizzled)
    const int tid  = threadIdx.x;
    const int tile = blockIdx.x & 31;
    const int h    = (blockIdx.x >> 5) & 3;
    const int b    = blockIdx.x >> 7;
    const int i0   = tile * 16;
    const int lane = tid & 63, wv = tid >> 6;

    for (int idx = tid; idx < 16*TT; idx += 256) {
        int i = idx / TT, t = idx - i*TT;
        ql[i][t] = qpack[((size_t)(b*SS + i0 + i)*HH + h)*TT + t];
    }

    u64 kr0[TT], kr1[TT];
    {
        const u64* kp0 = &kpack[((size_t)(b*SS + tid      )*HH + h)*TT];
        const u64* kp1 = &kpack[((size_t)(b*SS + tid + 256)*HH + h)*TT];
        #pragma unroll
        for (int t = 0; t < TT; ++t) { kr0[t] = kp0[t]; kr1[t] = kp1[t]; }
    }
    __syncthreads();

    // scores as integer counts
    for (int i = 0; i < 16; ++i) {
        int c0 = 0, c1 = 0;
        #pragma unroll
        for (int t = 0; t < TT; ++t) {
            u64 q = ql[i][t];
            c0 += __popcll(q & kr0[t]);
            c1 += __popcll(q & kr1[t]);
        }
        CP[i*SS + tid]       = (u16)c0;
        CP[i*SS + tid + 256] = (u16)c1;
    }
    __syncthreads();

    // softmax per row (wave wv owns rows wv*4..wv*4+3); write W f32, P bf16 swizzled
    for (int rr = 0; rr < 4; ++rr) {
        const int i = wv*4 + rr;
        float sv[8];
        float m = -1e30f;
        #pragma unroll
        for (int k2 = 0; k2 < 8; ++k2) {
            sv[k2] = (float)CP[i*SS + lane + 64*k2] * 0.125f;
            m = fmaxf(m, sv[k2]);
        }
        #pragma unroll
        for (int msk = 32; msk >= 1; msk >>= 1) m = fmaxf(m, __shfl_xor(m, msk, 64));
        float sum = 0.f;
        #pragma unroll
        for (int k2 = 0; k2 < 8; ++k2) { sv[k2] = expf(sv[k2] - m); sum += sv[k2]; }
        #pragma unroll
        for (int msk = 32; msk >= 1; msk >>= 1) sum += __shfl_xor(sum, msk, 64);
        float inv = 1.f / sum;
        size_t wbase = ((size_t)((b*HH + h)*SS) + i0 + i) * SS;
        #pragma unroll
        for (int k2 = 0; k2 < 8; ++k2) {
            int j = lane + 64*k2;
            float wval = sv[k2] * inv;
            Wout[wbase + j] = wval;
            CP[(i*SS + j) ^ ((i & 7) << 3)] = f2bf(wval);
        }
    }
    __syncthreads();

    // PV via mfma_f32_16x16x32_bf16: out tile 16 x 64, wave wv owns n-tile of 16
    const int n0 = wv * 16;
    const int mr = lane & 15;    // A row / B col / D col
    const int g  = lane >> 4;    // k-group
    float4_t acc = {0.f, 0.f, 0.f, 0.f};
    const u16* vb_base = vmb + (size_t)b*SS*DD + h*64 + n0 + mr;
    for (int ks = 0; ks < 16; ++ks) {
        int k = ks*32 + g*8;
        int aidx = (mr*SS + k) ^ ((mr & 7) << 3);
        short8 a = *reinterpret_cast<const short8*>(&CP[aidx]);
        union { u16 u[8]; short8 v; } bu;
        const u16* vb = vb_base + (size_t)k*DD;
        #pragma unroll
        for (int j = 0; j < 8; ++j) bu.u[j] = vb[(size_t)j*DD];
        acc = __builtin_amdgcn_mfma_f32_16x16x32_bf16(a, bu.v, acc, 0, 0, 0);
    }
    #pragma unroll
    for (int r = 0; r < 4; ++r) {
        int row = g*4 + r;   // D: row=(lane>>4)*4+reg, col=lane&15
        attn[(size_t)(b*SS + i0 + row)*DD + h*64 + n0 + mr] = acc[r];
    }
}

// ===================== Kernel D: out = attn @ Wo + bo =====================
// 512 blocks x 256 thr; 8 tokens/block; transposed LDS stage
__global__ __launch_bounds__(256) void k_outproj(
    const float* __restrict__ attn, const float* __restrict__ Wo,
    const float* __restrict__ bo, float* __restrict__ out)
{
    __shared__ float al[DD][8];
    const int tid  = threadIdx.x;
    const int tok0 = blockIdx.x * 8;
    #pragma unroll
    for (int m = 0; m < 8; ++m) al[tid][m] = attn[(size_t)(tok0+m)*DD + tid];
    __syncthreads();
    float acc[8] = {0,0,0,0,0,0,0,0};
    #pragma unroll 4
    for (int r = 0; r < DD; ++r) {
        float w = Wo[r*DD + tid];
        float4_t a0 = *reinterpret_cast<const float4_t*>(&al[r][0]);
        float4_t a1 = *reinterpret_cast<const float4_t*>(&al[r][4]);
        acc[0] += a0.x*w; acc[1] += a0.y*w; acc[2] += a0.z*w; acc[3] += a0.w*w;
        acc[4] += a1.x*w; acc[5] += a1.y*w; acc[6] += a1.z*w; acc[7] += a1.w*w;
    }
    float bb = bo[tid];
    #pragma unroll
    for (int i = 0; i < 8; ++i) out[(size_t)(tok0+i)*DD + tid] = acc[i] + bb;
}

extern "C" void kernel_launch(void* const* d_in, const int* in_sizes, int n_in,
                              void* d_out, int out_size, void* d_ws, size_t ws_size,
                              hipStream_t stream)
{
    (void)in_sizes; (void)n_in; (void)out_size; (void)ws_size;
    const float* x   = (const float*)d_in[0];
    const float* Wq  = (const float*)d_in[1];
    const float* Wk  = (const float*)d_in[2];
    const float* Wv  = (const float*)d_in[3];
    const float* Wo  = (const float*)d_in[4];
    const float* bo  = (const float*)d_in[5];
    const float* Wg1 = (const float*)d_in[6];
    const float* bg1 = (const float*)d_in[7];
    const float* Wg2 = (const float*)d_in[8];
    const float* bg2 = (const float*)d_in[9];
    const float* aq  = (const float*)d_in[10];
    const float* bq  = (const float*)d_in[11];
    const float* ak  = (const float*)d_in[12];
    const float* bk  = (const float*)d_in[13];
    const float* av  = (const float*)d_in[14];
    const float* bv  = (const float*)d_in[15];
    float* out = (float*)d_out;

    u64* qp = (u64*)d_ws;
    u64* kp = qp + (size_t)BS*HH*TT;
    u16* vmb = (u16*)(kp + (size_t)BS*HH*TT);
    float* attnbuf = (float*)(vmb + (size_t)BS*DD);

    k_gate<<<512, 256, 0, stream>>>(x, Wg1, bg1, Wg2, bg2, out + TI_OFF);
    k_reg<<<1, 256, 0, stream>>>(out + TI_OFF, out + REG_OFF);
    dim3 gproj(512, 3);
    k_proj_lif<<<gproj, 256, 0, stream>>>(x, Wq, Wk, Wv,
        aq, bq, ak, bk, av, bv, out + TI_OFF, qp, kp, vmb);
    k_attn<<<1024, 256, 0, stream>>>(qp, kp, vmb, out + W_OFF, attnbuf);
    k_outproj<<<512, 256, 0, stream>>>(attnbuf, Wo, bo, out);
}

// Round 5
// 102.868 us; speedup vs baseline: 1.2358x; 1.2358x over previous
//
#include <hip/hip_runtime.h>
#include <hip/hip_bf16.h>

typedef unsigned long long u64;
typedef unsigned short u16;
typedef __attribute__((ext_vector_type(8))) short short8;
typedef __attribute__((ext_vector_type(4))) float float4_t;

#define BB 8
#define SS 512
#define DD 256
#define HH 4
#define TT 20
#define BS (BB*SS)   /* 4096 tokens */

// d_out layout (floats): out[BS*DD], reg[1], Ti[BS], W[BB*HH*SS*SS]
#define REG_OFF (BS*DD)
#define TI_OFF  (REG_OFF+1)
#define W_OFF   (TI_OFF+BS)

static __device__ __forceinline__ u16 f2bf(float f) {
    __hip_bfloat16 h = __float2bfloat16(f);
    return *reinterpret_cast<u16*>(&h);
}

// ===================== Kernel G: gate MLP -> Ti =====================
// 1024 blocks x 256 thr; wave = 1 token (4 tokens/block)
__global__ __launch_bounds__(256) void k_gate(
    const float* __restrict__ x,
    const float* __restrict__ Wg1, const float* __restrict__ bg1,
    const float* __restrict__ Wg2, const float* __restrict__ bg2,
    float* __restrict__ ti_out)
{
    const int tid  = threadIdx.x;
    const int tok  = blockIdx.x * 4 + (tid >> 6);
    const int lane = tid & 63;
    const int c    = lane & 31;
    const int half = lane >> 5;

    const float* xr = x + (size_t)tok*DD + half*128;
    const float* wg = Wg1 + (size_t)half*128*32 + c;
    float acc = 0.f;
    #pragma unroll 4
    for (int i = 0; i < 32; ++i) {
        float4_t xv = *reinterpret_cast<const float4_t*>(xr + i*4);
        acc += xv.x * wg[(i*4+0)*32] + xv.y * wg[(i*4+1)*32]
             + xv.z * wg[(i*4+2)*32] + xv.w * wg[(i*4+3)*32];
    }
    acc += __shfl_xor(acc, 32, 64);   // combine K-halves (same c)
    acc += bg1[c];
    float hrelu = acc > 0.f ? acc : 0.f;
    float term  = hrelu * Wg2[c];
    #pragma unroll
    for (int msk = 16; msk >= 1; msk >>= 1) term += __shfl_xor(term, msk, 64);
    if (lane == 0) {
        float g  = term + bg2[0];
        float sg = 1.f / (1.f + expf(-g));
        int ti = (int)ceilf(sg * (float)TT);
        ti = ti < 1 ? 1 : (ti > TT ? TT : ti);
        ti_out[tok] = (float)ti;
    }
}

// ===================== Kernel A: one projection + LIF (split-K) =====================
// grid (512, 3): bx = token tile (8 tokens), by = projection (0=q,1=k,2=v)
__global__ __launch_bounds__(256) void k_proj_lif(
    const float* __restrict__ x, const float* __restrict__ Wq,
    const float* __restrict__ Wk, const float* __restrict__ Wv,
    const float* __restrict__ aq, const float* __restrict__ bq_,
    const float* __restrict__ ak, const float* __restrict__ bk_,
    const float* __restrict__ av, const float* __restrict__ bv_,
    const float* __restrict__ ti_in,
    u64* __restrict__ qpack, u64* __restrict__ kpack,
    u16* __restrict__ vmb)
{
    __shared__ __align__(16) union {
        float xt[DD][8];        // 8 KB: x transposed (row r, token m)
        float red[4][8][DD];    // 32 KB: per-wave partial sums
    } sm;
    __shared__ int til[8];
    const int tid  = threadIdx.x;
    const int proj = blockIdx.y;
    const int tok0 = blockIdx.x * 8;
    const int w = tid >> 6, l = tid & 63;

    #pragma unroll
    for (int m = 0; m < 8; ++m) sm.xt[tid][m] = x[(size_t)(tok0+m)*DD + tid];
    if (tid < 8) til[tid] = (int)ti_in[tok0 + tid];
    __syncthreads();

    const float* W    = proj == 0 ? Wq  : (proj == 1 ? Wk  : Wv);
    const float alpha = proj == 0 ? *aq : (proj == 1 ? *ak : *av);
    const float beta  = proj == 0 ? *bq_: (proj == 1 ? *bk_: *bv_);

    float4_t a[8];
    #pragma unroll
    for (int i = 0; i < 8; ++i) a[i] = (float4_t){0.f, 0.f, 0.f, 0.f};

    const float* Wp = W + (size_t)(w*64)*DD + l*4;
    #pragma unroll 4
    for (int r0 = 0; r0 < 64; ++r0) {
        float4_t wf = *reinterpret_cast<const float4_t*>(Wp + (size_t)r0*DD);
        int r = (w << 6) + r0;
        float4_t x0 = *reinterpret_cast<const float4_t*>(&sm.xt[r][0]);
        float4_t x1 = *reinterpret_cast<const float4_t*>(&sm.xt[r][4]);
        a[0] += wf*x0.x; a[1] += wf*x0.y; a[2] += wf*x0.z; a[3] += wf*x0.w;
        a[4] += wf*x1.x; a[5] += wf*x1.y; a[6] += wf*x1.z; a[7] += wf*x1.w;
    }
    __syncthreads();   // xt dead; safe to overwrite via union
    #pragma unroll
    for (int i = 0; i < 8; ++i)
        *reinterpret_cast<float4_t*>(&sm.red[w][i][l*4]) = a[i];
    __syncthreads();

    float val[8];
    #pragma unroll
    for (int i = 0; i < 8; ++i)
        val[i] = (sm.red[0][i][tid] + sm.red[1][i][tid])
               + (sm.red[2][i][tid] + sm.red[3][i][tid]);

    const int h = w;   // col = tid -> head = tid>>6, channel = lane
    if (proj < 2) {
        u64* pack = (proj == 0) ? qpack : kpack;
        for (int i = 0; i < 8; ++i) {
            const int ti = til[i];
            float vv = 0.f, cur = 0.f;
            u64 myw = 0ull;
            #pragma unroll
            for (int t = 0; t < TT; ++t) {
                cur = alpha*cur + val[i];
                vv  = beta*vv + cur;
                bool s = (vv >= 1.f);
                u64 bal = __ballot(s);
                if (s) vv = 0.f;
                if (l == t && t < ti) myw = bal;
            }
            if (l < TT)
                pack[((size_t)(tok0+i)*HH + h)*TT + l] = myw;
        }
    } else {
        for (int i = 0; i < 8; ++i) {
            const int ti = til[i];
            float vv = 0.f, cur = 0.f, cnt = 0.f;
            #pragma unroll
            for (int t = 0; t < TT; ++t) {
                cur = alpha*cur + val[i];
                vv  = beta*vv + cur;
                bool s = (vv >= 1.f);
                if (s) { vv = 0.f; if (t < ti) cnt += 1.f; }
            }
            vmb[(size_t)(tok0+i)*DD + tid] = f2bf(cnt * 0.05f);
        }
    }
}

// ===================== Kernel C: popcount scores + softmax + W + PV (MFMA) ===========
__global__ __launch_bounds__(256) void k_attn(
    const u64* __restrict__ qpack, const u64* __restrict__ kpack,
    const u16* __restrict__ vmb,
    float* __restrict__ Wout, float* __restrict__ attn)
{
    __shared__ u64 ql[16][TT];                 // 2.5 KB
    __shared__ __align__(16) u16 CP[16*SS];    // 16 KB: counts, then P (bf16, swizzled)
    const int tid  = threadIdx.x;
    const int tile = blockIdx.x & 31;
    const int h    = (blockIdx.x >> 5) & 3;
    const int b    = blockIdx.x >> 7;
    const int i0   = tile * 16;
    const int lane = tid & 63, wv = tid >> 6;

    for (int idx = tid; idx < 16*TT; idx += 256) {
        int i = idx / TT, t = idx - i*TT;
        ql[i][t] = qpack[((size_t)(b*SS + i0 + i)*HH + h)*TT + t];
    }

    u64 kr0[TT], kr1[TT];
    {
        const u64* kp0 = &kpack[((size_t)(b*SS + tid      )*HH + h)*TT];
        const u64* kp1 = &kpack[((size_t)(b*SS + tid + 256)*HH + h)*TT];
        #pragma unroll
        for (int t = 0; t < TT; ++t) { kr0[t] = kp0[t]; kr1[t] = kp1[t]; }
    }
    __syncthreads();

    // scores as integer counts
    for (int i = 0; i < 16; ++i) {
        int c0 = 0, c1 = 0;
        #pragma unroll
        for (int t = 0; t < TT; ++t) {
            u64 q = ql[i][t];
            c0 += __popcll(q & kr0[t]);
            c1 += __popcll(q & kr1[t]);
        }
        CP[i*SS + tid]       = (u16)c0;
        CP[i*SS + tid + 256] = (u16)c1;
    }
    __syncthreads();

    // softmax per row (wave wv owns rows wv*4..wv*4+3); write W f32, P bf16 swizzled
    for (int rr = 0; rr < 4; ++rr) {
        const int i = wv*4 + rr;
        float sv[8];
        float m = -1e30f;
        #pragma unroll
        for (int k2 = 0; k2 < 8; ++k2) {
            sv[k2] = (float)CP[i*SS + lane + 64*k2] * 0.125f;
            m = fmaxf(m, sv[k2]);
        }
        #pragma unroll
        for (int msk = 32; msk >= 1; msk >>= 1) m = fmaxf(m, __shfl_xor(m, msk, 64));
        float sum = 0.f;
        #pragma unroll
        for (int k2 = 0; k2 < 8; ++k2) { sv[k2] = expf(sv[k2] - m); sum += sv[k2]; }
        #pragma unroll
        for (int msk = 32; msk >= 1; msk >>= 1) sum += __shfl_xor(sum, msk, 64);
        float inv = 1.f / sum;
        size_t wbase = ((size_t)((b*HH + h)*SS) + i0 + i) * SS;
        #pragma unroll
        for (int k2 = 0; k2 < 8; ++k2) {
            int j = lane + 64*k2;
            float wval = sv[k2] * inv;
            Wout[wbase + j] = wval;
            CP[(i*SS + j) ^ ((i & 7) << 3)] = f2bf(wval);
        }
    }
    __syncthreads();

    // PV via mfma_f32_16x16x32_bf16: out tile 16 x 64, wave wv owns n-tile of 16
    const int n0 = wv * 16;
    const int mr = lane & 15;    // A row / B col / D col
    const int g  = lane >> 4;    // k-group
    float4_t acc = {0.f, 0.f, 0.f, 0.f};
    const u16* vb_base = vmb + (size_t)b*SS*DD + h*64 + n0 + mr;
    for (int ks = 0; ks < 16; ++ks) {
        int k = ks*32 + g*8;
        int aidx = (mr*SS + k) ^ ((mr & 7) << 3);
        short8 a = *reinterpret_cast<const short8*>(&CP[aidx]);
        union { u16 u[8]; short8 v; } bu;
        const u16* vb = vb_base + (size_t)k*DD;
        #pragma unroll
        for (int j = 0; j < 8; ++j) bu.u[j] = vb[(size_t)j*DD];
        acc = __builtin_amdgcn_mfma_f32_16x16x32_bf16(a, bu.v, acc, 0, 0, 0);
    }
    #pragma unroll
    for (int r = 0; r < 4; ++r) {
        int row = g*4 + r;   // D: row=(lane>>4)*4+reg, col=lane&15
        attn[(size_t)(b*SS + i0 + row)*DD + h*64 + n0 + mr] = acc[r];
    }
}

// ===================== Kernel D: out = attn @ Wo + bo (split-K) + reg =====================
__global__ __launch_bounds__(256) void k_outproj(
    const float* __restrict__ attn, const float* __restrict__ Wo,
    const float* __restrict__ bo, const float* __restrict__ ti,
    float* __restrict__ out)
{
    __shared__ __align__(16) union {
        float xt[DD][8];
        float red[4][8][DD];
    } sm;
    __shared__ float ps[4];
    const int tid  = threadIdx.x;
    const int tok0 = blockIdx.x * 8;
    const int w = tid >> 6, l = tid & 63;

    #pragma unroll
    for (int m = 0; m < 8; ++m) sm.xt[tid][m] = attn[(size_t)(tok0+m)*DD + tid];
    __syncthreads();

    float4_t a[8];
    #pragma unroll
    for (int i = 0; i < 8; ++i) a[i] = (float4_t){0.f, 0.f, 0.f, 0.f};
    const float* Wp = Wo + (size_t)(w*64)*DD + l*4;
    #pragma unroll 4
    for (int r0 = 0; r0 < 64; ++r0) {
        float4_t wf = *reinterpret_cast<const float4_t*>(Wp + (size_t)r0*DD);
        int r = (w << 6) + r0;
        float4_t x0 = *reinterpret_cast<const float4_t*>(&sm.xt[r][0]);
        float4_t x1 = *reinterpret_cast<const float4_t*>(&sm.xt[r][4]);
        a[0] += wf*x0.x; a[1] += wf*x0.y; a[2] += wf*x0.z; a[3] += wf*x0.w;
        a[4] += wf*x1.x; a[5] += wf*x1.y; a[6] += wf*x1.z; a[7] += wf*x1.w;
    }
    __syncthreads();
    #pragma unroll
    for (int i = 0; i < 8; ++i)
        *reinterpret_cast<float4_t*>(&sm.red[w][i][l*4]) = a[i];
    __syncthreads();

    float bb = bo[tid];
    #pragma unroll
    for (int i = 0; i < 8; ++i) {
        float v = (sm.red[0][i][tid] + sm.red[1][i][tid])
                + (sm.red[2][i][tid] + sm.red[3][i][tid]);
        out[(size_t)(tok0+i)*DD + tid] = v + bb;
    }

    if (blockIdx.x == 0) {   // fold reg = 1e-3 * mean(Ti)
        float s = 0.f;
        for (int m = 0; m < 16; ++m) s += ti[m*256 + tid];
        #pragma unroll
        for (int msk = 32; msk >= 1; msk >>= 1) s += __shfl_xor(s, msk, 64);
        if ((tid & 63) == 0) ps[tid >> 6] = s;
        __syncthreads();
        if (tid == 0) out[REG_OFF] = 1e-3f * (ps[0]+ps[1]+ps[2]+ps[3]) / 4096.f;
    }
}

extern "C" void kernel_launch(void* const* d_in, const int* in_sizes, int n_in,
                              void* d_out, int out_size, void* d_ws, size_t ws_size,
                              hipStream_t stream)
{
    (void)in_sizes; (void)n_in; (void)out_size; (void)ws_size;
    const float* x   = (const float*)d_in[0];
    const float* Wq  = (const float*)d_in[1];
    const float* Wk  = (const float*)d_in[2];
    const float* Wv  = (const float*)d_in[3];
    const float* Wo  = (const float*)d_in[4];
    const float* bo  = (const float*)d_in[5];
    const float* Wg1 = (const float*)d_in[6];
    const float* bg1 = (const float*)d_in[7];
    const float* Wg2 = (const float*)d_in[8];
    const float* bg2 = (const float*)d_in[9];
    const float* aq  = (const float*)d_in[10];
    const float* bq  = (const float*)d_in[11];
    const float* ak  = (const float*)d_in[12];
    const float* bk  = (const float*)d_in[13];
    const float* av  = (const float*)d_in[14];
    const float* bv  = (const float*)d_in[15];
    float* out = (float*)d_out;

    u64* qp = (u64*)d_ws;
    u64* kp = qp + (size_t)BS*HH*TT;
    u16* vmb = (u16*)(kp + (size_t)BS*HH*TT);
    float* attnbuf = (float*)(vmb + (size_t)BS*DD);

    k_gate<<<1024, 256, 0, stream>>>(x, Wg1, bg1, Wg2, bg2, out + TI_OFF);
    dim3 gproj(512, 3);
    k_proj_lif<<<gproj, 256, 0, stream>>>(x, Wq, Wk, Wv,
        aq, bq, ak, bk, av, bv, out + TI_OFF, qp, kp, vmb);
    k_attn<<<1024, 256, 0, stream>>>(qp, kp, vmb, out + W_OFF, attnbuf);
    k_outproj<<<512, 256, 0, stream>>>(attnbuf, Wo, bo, out + TI_OFF, out);
}